// Round 11
// baseline (455.480 us; speedup 1.0000x reference)
//
#include <hip/hip_runtime.h>
#include <math.h>

// Match numpy's non-FMA evaluation of the distance formula (ranking fidelity).
#pragma clang fp contract(off)

// ============================================================================
// ROUND 11: COUNTER-CAPTURE PROBE. Identical to R9 except knn's scan+select
// phases run TWICE internally (emit once; output bit-identical). This pushes
// knn's dispatch duration above the ~165 us harness fills so it finally
// surfaces in the top-5 counter table with VGPR/VALUBusy/LDS/FETCH data.
// asm volatile keepalives prevent DCE of the first repetition.
// ============================================================================

#define NPTS 4096
#define KNN  16
#define RPBK 32       // rows per block in knn kernel (16 waves x 2 rows/wave)
#define KT   1024     // knn threads per block
#define CAP  128      // filtered-candidate list capacity per row (knn phase 2)
#define CAPIN 64      // incoming-edge bucket capacity per row
#define SPILLCAP 262144
#define RROWS 4       // rows per block in row kernel

// native 4-float vector for nontemporal builtins
typedef float nfloat4 __attribute__((ext_vector_type(4)));

// ordered-uint transform: monotone map f32 -> u32 (canonicalize -0 -> +0 first)
__device__ __forceinline__ unsigned okey(float f) {
    f = f + 0.0f;
    unsigned u = __float_as_uint(f);
    return u ^ (((unsigned)((int)u >> 31)) | 0x80000000u);
}

__device__ __forceinline__ unsigned long long wmin64(unsigned long long v) {
    for (int o = 32; o > 0; o >>= 1) { unsigned long long w = __shfl_xor(v, o); v = w < v ? w : v; }
    return v;
}

// dis recompute (bitwise == old dis_kernel expression)
__device__ __forceinline__ float disv(const float* __restrict__ Dsum, int i) {
    return 1.0f / sqrtf(fmaxf(Dsum[i], 1e-6f));
}

// ---------------------------------------------------------------------------
__global__ void zero_kernel(float* __restrict__ p, int n) {
    int i = blockIdx.x * blockDim.x + threadIdx.x;
    if (i < n) p[i] = 0.0f;
}

// ---------------------------------------------------------------------------
// T = 16th smallest (by (value, lane)) of the 64 per-lane values.
// ---------------------------------------------------------------------------
__device__ __forceinline__ float thresh16(float k, int lane) {
    int rank = 0;
#pragma unroll
    for (int s = 0; s < 64; ++s) {
        float ks = __shfl(k, s);
        rank += (ks < k || (ks == k && s < lane)) ? 1 : 0;
    }
    unsigned long long m = __ballot(rank == 15);
    return __shfl(k, __ffsll(m) - 1);
}

// ---------------------------------------------------------------------------
// Exact top-16 of the candidate list by (d2, idx); winner lands on lane r.
// ---------------------------------------------------------------------------
__device__ __forceinline__ int select16(const float* __restrict__ sx,
                                        const float* __restrict__ sy,
                                        const float* __restrict__ sz,
                                        const int* __restrict__ list,
                                        int cnt2, float4 P, int lane) {
    if (cnt2 <= 64) {
        float key = __builtin_huge_valf();
        int m = -1;
        if (lane < cnt2) {
            m = list[lane];
            float qx = sx[m], qy = sy[m], qz = sz[m];
            float qw = (qx * qx + qy * qy) + qz * qz;
            float dot = (P.x * qx + P.y * qy) + P.z * qz;
            key = (P.w + qw) - 2.0f * dot;
        }
        int rank = 0;
#pragma unroll
        for (int s = 0; s < 64; ++s) {
            float ks = __shfl(key, s);
            rank += (ks < key || (ks == key && s < lane)) ? 1 : 0;
        }
        return __builtin_amdgcn_ds_permute(rank << 2, m);
    }
    if (cnt2 <= CAP) {
        unsigned long long e0 = ~0ull, e1 = ~0ull;
        if (lane < cnt2) {
            int m = list[lane];
            float qx = sx[m], qy = sy[m], qz = sz[m];
            float qw = (qx * qx + qy * qy) + qz * qz;
            float dot = (P.x * qx + P.y * qy) + P.z * qz;
            float d2  = (P.w + qw) - 2.0f * dot;
            e0 = ((unsigned long long)okey(d2) << 32) | (unsigned)m;
        }
        if (lane + 64 < cnt2) {
            int m = list[lane + 64];
            float qx = sx[m], qy = sy[m], qz = sz[m];
            float qw = (qx * qx + qy * qy) + qz * qz;
            float dot = (P.x * qx + P.y * qy) + P.z * qz;
            float d2  = (P.w + qw) - 2.0f * dot;
            e1 = ((unsigned long long)okey(d2) << 32) | (unsigned)m;
        }
        int selm = -1;
        unsigned long long c = e0 < e1 ? e0 : e1;
        for (int r = 0; r < KNN; ++r) {
            unsigned long long mn = wmin64(c);
            if (c == mn) {
                if (e0 == mn) e0 = ~0ull; else e1 = ~0ull;
                c = e0 < e1 ? e0 : e1;
            }
            if (lane == r) selm = (int)(unsigned)(mn & 0xFFFFFFFFull);
        }
        return selm;
    }
    unsigned long long last = 0; int selm = -1;
    for (int r = 0; r < KNN; ++r) {
        unsigned long long bestp = ~0ull;
        for (int i = 0; i < NPTS / 64; ++i) {
            int m = i * 64 + lane;
            float qx = sx[m], qy = sy[m], qz = sz[m];
            float qw = (qx * qx + qy * qy) + qz * qz;
            float dot = (P.x * qx + P.y * qy) + P.z * qz;
            float d2  = (P.w + qw) - 2.0f * dot;
            unsigned long long key = ((unsigned long long)okey(d2) << 32) | (unsigned)m;
            if (key > last && key < bestp) bestp = key;
        }
        unsigned long long mn = wmin64(bestp);
        if (lane == r) selm = (int)(unsigned)(mn & 0xFFFFFFFFull);
        last = mn;
    }
    return selm;
}

// ---------------------------------------------------------------------------
__device__ __forceinline__ void emit_row(int rowg, int b, int selm, float4 P,
                                         const float* __restrict__ sx,
                                         const float* __restrict__ sy,
                                         const float* __restrict__ sz,
                                         float* __restrict__ Dsum,
                                         int* __restrict__ idx_out,
                                         float* __restrict__ w_out,
                                         int* __restrict__ cnt,
                                         int* __restrict__ inc,
                                         int* __restrict__ spillc,
                                         int* __restrict__ spill,
                                         int do_inc, int lane) {
    float wgt = 0.0f;
    if (lane < KNN) {
        int j = selm;
        float dx = P.x - sx[j], dy = P.y - sy[j], dz = P.z - sz[j];
        float dist2 = (dx * dx + dy * dy) + dz * dz;                // numpy order
        wgt = expf(-(dist2 * 0.5f));                                // == -dist2/2.0
        size_t base = (size_t)rowg * KNN + lane;
        idx_out[base] = j;
        w_out[base]   = wgt;
        int jg = (b << 12) + j;
        atomicAdd(&Dsum[jg], 0.5f * wgt);                           // transpose half
        if (do_inc) {
            int pos = atomicAdd(&cnt[jg], 1);
            if (pos < CAPIN) {
                inc[(size_t)jg * CAPIN + pos] = (int)base;
            } else {
                int sp = atomicAdd(spillc, 1);
                if (sp < SPILLCAP) spill[sp] = (int)base;
            }
        }
    }
    float rs = wgt;
    for (int o = 32; o > 0; o >>= 1) rs += __shfl_xor(rs, o);
    if (lane == 0) atomicAdd(&Dsum[rowg], 0.5f * rs);               // outgoing half
}

// ---------------------------------------------------------------------------
// KNN (R9 structure) with the scan+select phases repeated 2x for the probe.
// emit runs once -> output bit-identical to R9.
// ---------------------------------------------------------------------------
__global__ __launch_bounds__(KT, 8) void knn_kernel(const float* __restrict__ xyz,
                                                    float* __restrict__ Dsum,
                                                    int* __restrict__ idx_out,
                                                    float* __restrict__ w_out,
                                                    int* __restrict__ cnt,
                                                    int* __restrict__ inc,
                                                    int* __restrict__ spillc,
                                                    int* __restrict__ spill,
                                                    int do_inc) {
    __shared__ float sx[NPTS], sy[NPTS], sz[NPTS];   // 48 KB
    __shared__ int   lists[RPBK][CAP];               // 16 KB

    const int t    = threadIdx.x;
    const int lane = t & 63;
    const int wv   = t >> 6;                              // wave id 0..15
    const int row0 = blockIdx.x * RPBK + 2 * wv;          // this wave: row0, row0+1
    const int b    = row0 >> 12;
    const float* X = xyz + (size_t)b * 3 * NPTS;

    for (int i = t; i < NPTS; i += KT) {
        sx[i] = X[i]; sy[i] = X[NPTS + i]; sz[i] = X[2 * NPTS + i];
    }
    __syncthreads();

    const int ra = row0 & (NPTS - 1), rb = (row0 + 1) & (NPTS - 1);
    float4 PA, PB;
    PA.x = sx[ra]; PA.y = sy[ra]; PA.z = sz[ra];
    PA.w = (PA.x * PA.x + PA.y * PA.y) + PA.z * PA.z;    // numpy order
    PB.x = sx[rb]; PB.y = sy[rb]; PB.z = sz[rb];
    PB.w = (PB.x * PB.x + PB.y * PB.y) + PB.z * PB.z;

    int* listA = &lists[2 * wv][0];
    int* listB = &lists[2 * wv + 1][0];
    int selA = 0, selB = 0;

    // ======== PROBE: phases 1-3 repeated twice (deterministic, same data,
    // same LDS region per wave; reps sequential). Keepalives stop DCE. ======
#pragma unroll 1
    for (int rep = 0; rep < 2; ++rep) {
        // ---- phase 1: per-lane chunk minima (both rows per point read) ----
        float bA = __builtin_huge_valf(), bB = __builtin_huge_valf();
        for (int i = 0; i < NPTS / 64; ++i) {
            int m = i * 64 + lane;
            float qx = sx[m], qy = sy[m], qz = sz[m];
            float qw = (qx * qx + qy * qy) + qz * qz;                  // numpy order
            float dotA = (PA.x * qx + PA.y * qy) + PA.z * qz;          // einsum order
            float d2A  = (PA.w + qw) - 2.0f * dotA;                    // (sq+sq)-2dot
            float dotB = (PB.x * qx + PB.y * qy) + PB.z * qz;
            float d2B  = (PB.w + qw) - 2.0f * dotB;
            bA = fminf(bA, d2A);
            bB = fminf(bB, d2B);
        }
        const float TA = thresh16(bA, lane);     // >= 16th smallest d2, row A
        const float TB = thresh16(bB, lane);

        // ---- phase 2: filter candidates with d2 <= T into LDS lists ----
        int cA = 0, cB = 0;
        for (int i = 0; i < NPTS / 64; ++i) {
            int m = i * 64 + lane;
            float qx = sx[m], qy = sy[m], qz = sz[m];
            float qw = (qx * qx + qy * qy) + qz * qz;
            float dotA = (PA.x * qx + PA.y * qy) + PA.z * qz;
            float d2A  = (PA.w + qw) - 2.0f * dotA;
            float dotB = (PB.x * qx + PB.y * qy) + PB.z * qz;
            float d2B  = (PB.w + qw) - 2.0f * dotB;
            bool pA = d2A <= TA;
            unsigned long long balA = __ballot(pA);
            if (pA) {
                int pos = cA + __popcll(balA & ((1ull << lane) - 1ull));
                if (pos < CAP) listA[pos] = m;
            }
            cA += (int)__popcll(balA);
            bool pB = d2B <= TB;
            unsigned long long balB = __ballot(pB);
            if (pB) {
                int pos = cB + __popcll(balB & ((1ull << lane) - 1ull));
                if (pos < CAP) listB[pos] = m;
            }
            cB += (int)__popcll(balB);
        }

        // ---- phase 3: exact top-16 per row ----
        selA = select16(sx, sy, sz, listA, cA, PA, lane);
        selB = select16(sx, sy, sz, listB, cB, PB, lane);
        asm volatile("" :: "v"(selA), "v"(selB));    // keep rep 0 live (no DCE)
    }

    // ---- outputs (once) ----
    emit_row(row0,     b, selA, PA, sx, sy, sz, Dsum, idx_out, w_out,
             cnt, inc, spillc, spill, do_inc, lane);
    emit_row(row0 + 1, b, selB, PB, sx, sy, sz, Dsum, idx_out, w_out,
             cnt, inc, spillc, spill, do_inc, lane);
}

// ---------------------------------------------------------------------------
// row_kernel (unchanged from R9, single launch)
// ---------------------------------------------------------------------------
__global__ __launch_bounds__(1024, 4) void row_kernel(const int* __restrict__ idxb,
                                                      const float* __restrict__ wb,
                                                      const float* __restrict__ Dsum,
                                                      const int* __restrict__ cnt,
                                                      const int* __restrict__ inc,
                                                      const int* __restrict__ spillc,
                                                      const int* __restrict__ spill,
                                                      float* __restrict__ L) {
    __shared__ float row[RROWS * NPTS];          // 64 KB
    const int r0 = blockIdx.x * RROWS;           // first global row
    const int b  = r0 >> 12;

    float4* row4 = (float4*)row;
    for (int i = threadIdx.x; i < RROWS * NPTS / 4; i += 1024)
        row4[i] = make_float4(0.0f, 0.0f, 0.0f, 0.0f);
    __syncthreads();

    const int rr = threadIdx.x >> 8;             // 0..RROWS-1
    const int tt = threadIdx.x & 255;
    const int r  = r0 + rr;
    float* myrow = row + rr * NPTS;
    const float dn = disv(Dsum, r);

    if (tt < KNN) {                              // outgoing (unique cols)
        int g = r * KNN + tt;
        int j = idxb[g];
        float v = -0.5f * wb[g] * dn * disv(Dsum, (b << 12) + j);
        atomicAdd(&myrow[j], v);
    }
    int c = cnt[r];
    if (c > CAPIN) c = CAPIN;                    // overflow -> spill drain below
    for (int i = tt; i < c; i += 256) {          // incoming bucket
        int g   = inc[(size_t)r * CAPIN + i];
        int src = g >> 4;
        float v = -0.5f * wb[g] * disv(Dsum, src) * dn;
        atomicAdd(&myrow[src & (NPTS - 1)], v);
    }

    int sc = spillc[0];
    if (sc > 0) {
        if (sc > SPILLCAP) sc = SPILLCAP;
        for (int i = threadIdx.x; i < sc; i += 1024) {
            int g   = spill[i];
            int src = g >> 4;
            int jg  = ((src >> 12) << 12) + idxb[g];     // target row global
            if (jg >= r0 && jg < r0 + RROWS) {
                float v = -0.5f * wb[g] * disv(Dsum, src) * disv(Dsum, jg);
                atomicAdd(&row[(jg - r0) * NPTS + (src & (NPTS - 1))], v);
            }
        }
    }
    __syncthreads();

    const int n0 = r0 & (NPTS - 1);
    nfloat4* Lr = (nfloat4*)(L + (size_t)b * NPTS * NPTS + (size_t)n0 * NPTS);
    const nfloat4* row4n = (const nfloat4*)row;
    for (int q = threadIdx.x; q < RROWS * NPTS / 4; q += 1024) {
        nfloat4 v = row4n[q];
        int n = n0 + (q >> 10);                  // 1024 float4 per row
        if ((q & 1023) == (n >> 2)) v[n & 3] += 1.0f;
        __builtin_nontemporal_store(v, &Lr[q]);
    }
}

// ---------------------------------------------------------------------------
// Fallback path (small workspace): dense fill + global-atomic scatter.
// ---------------------------------------------------------------------------
__global__ void dis_kernel(const float* __restrict__ Dsum, float* __restrict__ dis, int n) {
    int i = blockIdx.x * blockDim.x + threadIdx.x;
    if (i < n) dis[i] = 1.0f / sqrtf(fmaxf(Dsum[i], 1e-6f));
}

__global__ __launch_bounds__(256) void fill_kernel(float4* __restrict__ L4, size_t T4) {
    size_t g4     = (size_t)blockIdx.x * blockDim.x + threadIdx.x;
    size_t stride = (size_t)gridDim.x * blockDim.x;
    for (; g4 < T4; g4 += stride) {
        size_t g = g4 << 2;
        int o    = (int)(g & (size_t)(NPTS * (size_t)NPTS - 1));
        int row  = o >> 12;
        int col0 = o & (NPTS - 1);
        float4 v;
        v.x = (row == col0    ) ? 1.0f : 0.0f;
        v.y = (row == col0 + 1) ? 1.0f : 0.0f;
        v.z = (row == col0 + 2) ? 1.0f : 0.0f;
        v.w = (row == col0 + 3) ? 1.0f : 0.0f;
        L4[g4] = v;
    }
}

__global__ __launch_bounds__(256) void scatter_kernel(const int* __restrict__ idxb,
                                                      const float* __restrict__ wb,
                                                      const float* __restrict__ dis,
                                                      float* __restrict__ L) {
    int g   = blockIdx.x * 256 + threadIdx.x;
    int row = g >> 4;
    int b   = row >> 12;
    int n   = row & (NPTS - 1);
    int j   = idxb[g];
    float v = -0.5f * wb[g] * dis[row] * dis[(b << 12) + j];
    float* Lb = L + (size_t)b * NPTS * NPTS;
    atomicAdd(Lb + (size_t)n * NPTS + j, v);
    atomicAdd(Lb + (size_t)j * NPTS + n, v);
}

// ---------------------------------------------------------------------------
extern "C" void kernel_launch(void* const* d_in, const int* in_sizes, int n_in,
                              void* d_out, int out_size, void* d_ws, size_t ws_size,
                              hipStream_t stream) {
    const float* xyz = (const float*)d_in[0];
    const int B  = in_sizes[0] / (3 * NPTS);            // 4
    const int BN = B * NPTS;                            // 16384

    float* Dsum   = (float*)d_ws;
    int*   cnt    = (int*)(Dsum + BN);
    int*   spillc = cnt + BN;
    int*   idxb   = (int*)(spillc + 16);
    float* wb     = (float*)(idxb + (size_t)BN * KNN);
    int*   inc    = (int*)(wb + (size_t)BN * KNN);
    int*   spill  = inc + (size_t)BN * CAPIN;
    float* L      = (float*)d_out;

    size_t need = ((size_t)BN * (2 + 2 * KNN + CAPIN) + 16 + SPILLCAP) * 4;
    const int fused = (ws_size >= need);

    if (fused) {
        int nz = 2 * BN + 16;                           // Dsum + cnt + spillc
        zero_kernel<<<(nz + 255) / 256, 256, 0, stream>>>(Dsum, nz);
        knn_kernel<<<BN / RPBK, KT, 0, stream>>>(xyz, Dsum, idxb, wb,
                                                 cnt, inc, spillc, spill, 1);
        row_kernel<<<BN / RROWS, 1024, 0, stream>>>(idxb, wb, Dsum,
                                                    cnt, inc, spillc, spill, L);
    } else {
        // fallback: fill + scatter (~2.25 MB workspace)
        float* fDsum = (float*)d_ws;
        float* fdis  = fDsum + BN;
        int*   fidx  = (int*)(fdis + BN);
        float* fwb   = (float*)(fidx + (size_t)BN * KNN);
        zero_kernel<<<BN / 256, 256, 0, stream>>>(fDsum, BN);
        knn_kernel<<<BN / RPBK, KT, 0, stream>>>(xyz, fDsum, fidx, fwb,
                                                 nullptr, nullptr, nullptr, nullptr, 0);
        dis_kernel<<<BN / 256, 256, 0, stream>>>(fDsum, fdis, BN);
        size_t T4 = (size_t)B * NPTS * NPTS / 4;
        fill_kernel<<<8192, 256, 0, stream>>>((float4*)d_out, T4);
        scatter_kernel<<<(BN * KNN) / 256, 256, 0, stream>>>(fidx, fwb, fdis, L);
    }
}

// Round 12
// 342.786 us; speedup vs baseline: 1.3288x; 1.3288x over previous
//
#include <hip/hip_runtime.h>
#include <math.h>

// Match numpy's non-FMA evaluation of the distance formula (ranking fidelity).
// NOTE: the FILTER phases deliberately use explicit fmaf (different rounding)
// with a slacked threshold -- they only need a SUPERSET of the true top-16.
// All final keys/weights (select16, emit_row) use the canonical contract-off
// expressions, so selection order and output values match lax.top_k exactly.
#pragma clang fp contract(off)

#define NPTS 4096
#define KNN  16
#define RW   4        // rows per wave in knn
#define RPBK 64       // rows per block (16 waves x 4 rows)
#define KT   1024     // knn threads per block
#define CAP  64       // candidate list capacity (E[cnt]~18; >64 -> exact rescan)
#define CAPIN 64      // incoming-edge bucket capacity per row
#define SPILLCAP 262144
#define RROWS 4       // rows per block in row kernel

// native 4-float vector for nontemporal builtins
typedef float nfloat4 __attribute__((ext_vector_type(4)));

// ordered-uint transform: monotone map f32 -> u32 (canonicalize -0 -> +0 first)
__device__ __forceinline__ unsigned okey(float f) {
    f = f + 0.0f;
    unsigned u = __float_as_uint(f);
    return u ^ (((unsigned)((int)u >> 31)) | 0x80000000u);
}

__device__ __forceinline__ unsigned long long wmin64(unsigned long long v) {
    for (int o = 32; o > 0; o >>= 1) { unsigned long long w = __shfl_xor(v, o); v = w < v ? w : v; }
    return v;
}

// dis recompute (bitwise == old dis_kernel expression)
__device__ __forceinline__ float disv(const float* __restrict__ Dsum, int i) {
    return 1.0f / sqrtf(fmaxf(Dsum[i], 1e-6f));
}

// ---------------------------------------------------------------------------
__global__ void zero_kernel(float* __restrict__ p, int n) {
    int i = blockIdx.x * blockDim.x + threadIdx.x;
    if (i < n) p[i] = 0.0f;
}

// ---------------------------------------------------------------------------
// T = 16th smallest (by (value, lane)) of the 64 per-lane values.
// ---------------------------------------------------------------------------
__device__ __forceinline__ float thresh16(float k, int lane) {
    int rank = 0;
#pragma unroll
    for (int s = 0; s < 64; ++s) {
        float ks = __shfl(k, s);
        rank += (ks < k || (ks == k && s < lane)) ? 1 : 0;
    }
    unsigned long long m = __ballot(rank == 15);
    return __shfl(k, __ffsll(m) - 1);
}

// ---------------------------------------------------------------------------
// Exact top-16 of the candidate list by canonical (d2, idx); winner -> lane r.
// Fast path (cnt <= 64): rank + ds_permute (list is ascending in idx).
// Fallback (cnt > 64, astronomically rare): exact 16-round full rescan.
// ---------------------------------------------------------------------------
__device__ __forceinline__ int select16(const float* __restrict__ sx,
                                        const float* __restrict__ sy,
                                        const float* __restrict__ sz,
                                        const int* __restrict__ list,
                                        int cnt2, float4 P, int lane) {
    if (cnt2 <= 64) {
        float key = __builtin_huge_valf();
        int m = -1;
        if (lane < cnt2) {
            m = list[lane];
            float qx = sx[m], qy = sy[m], qz = sz[m];
            float qw = (qx * qx + qy * qy) + qz * qz;       // canonical
            float dot = (P.x * qx + P.y * qy) + P.z * qz;   // canonical
            key = (P.w + qw) - 2.0f * dot;                  // canonical
        }
        int rank = 0;
#pragma unroll
        for (int s = 0; s < 64; ++s) {
            float ks = __shfl(key, s);
            rank += (ks < key || (ks == key && s < lane)) ? 1 : 0;
        }
        return __builtin_amdgcn_ds_permute(rank << 2, m);
    }
    // exact full-rescan fallback (canonical keys)
    unsigned long long last = 0; int selm = -1;
    for (int r = 0; r < KNN; ++r) {
        unsigned long long bestp = ~0ull;
        for (int i = 0; i < NPTS / 64; ++i) {
            int m = i * 64 + lane;
            float qx = sx[m], qy = sy[m], qz = sz[m];
            float qw = (qx * qx + qy * qy) + qz * qz;
            float dot = (P.x * qx + P.y * qy) + P.z * qz;
            float d2  = (P.w + qw) - 2.0f * dot;
            unsigned long long key = ((unsigned long long)okey(d2) << 32) | (unsigned)m;
            if (key > last && key < bestp) bestp = key;
        }
        unsigned long long mn = wmin64(bestp);
        if (lane == r) selm = (int)(unsigned)(mn & 0xFFFFFFFFull);
        last = mn;
    }
    return selm;
}

// ---------------------------------------------------------------------------
__device__ __forceinline__ void emit_row(int rowg, int b, int selm, float4 P,
                                         const float* __restrict__ sx,
                                         const float* __restrict__ sy,
                                         const float* __restrict__ sz,
                                         float* __restrict__ Dsum,
                                         int* __restrict__ idx_out,
                                         float* __restrict__ w_out,
                                         int* __restrict__ cnt,
                                         int* __restrict__ inc,
                                         int* __restrict__ spillc,
                                         int* __restrict__ spill,
                                         int do_inc, int lane) {
    float wgt = 0.0f;
    if (lane < KNN) {
        int j = selm;
        float dx = P.x - sx[j], dy = P.y - sy[j], dz = P.z - sz[j];
        float dist2 = (dx * dx + dy * dy) + dz * dz;                // numpy order
        wgt = expf(-(dist2 * 0.5f));                                // == -dist2/2.0
        size_t base = (size_t)rowg * KNN + lane;
        idx_out[base] = j;
        w_out[base]   = wgt;
        int jg = (b << 12) + j;
        atomicAdd(&Dsum[jg], 0.5f * wgt);                           // transpose half
        if (do_inc) {
            int pos = atomicAdd(&cnt[jg], 1);
            if (pos < CAPIN) {
                inc[(size_t)jg * CAPIN + pos] = (int)base;
            } else {
                int sp = atomicAdd(spillc, 1);
                if (sp < SPILLCAP) spill[sp] = (int)base;
            }
        }
    }
    float rs = wgt;
    for (int o = 32; o > 0; o >>= 1) rs += __shfl_xor(rs, o);
    if (lane == 0) atomicAdd(&Dsum[rowg], 0.5f * rs);               // outgoing half
}

// ---------------------------------------------------------------------------
// KNN: FOUR rows per wave; scan phases use explicit FMA (half the VALU ops)
// with a slack-inflated threshold so the candidate set is provably a superset
// of the canonical top-16; final selection is canonical. R11 PMC: VALUBusy
// 72% -> instruction-bound; this cuts scan instructions ~45%.
// LDS: 48 KB pts + 16 KB lists = 64 KB decl (+16 rt = 80) -> 2 blocks/CU,
// 8 waves/SIMD. launch_bounds(.,8) caps VGPR at 64 (R11 measured 32 @ 2-row).
// ---------------------------------------------------------------------------
__global__ __launch_bounds__(KT, 8) void knn_kernel(const float* __restrict__ xyz,
                                                    float* __restrict__ Dsum,
                                                    int* __restrict__ idx_out,
                                                    float* __restrict__ w_out,
                                                    int* __restrict__ cnt,
                                                    int* __restrict__ inc,
                                                    int* __restrict__ spillc,
                                                    int* __restrict__ spill,
                                                    int do_inc) {
    __shared__ float sx[NPTS], sy[NPTS], sz[NPTS];   // 48 KB
    __shared__ int   lists[RPBK][CAP];               // 16 KB

    const int t    = threadIdx.x;
    const int lane = t & 63;
    const int wv   = t >> 6;                              // wave id 0..15
    const int row0 = blockIdx.x * RPBK + wv * RW;         // 4 consecutive rows
    const int b    = row0 >> 12;
    const float* X = xyz + (size_t)b * 3 * NPTS;

    for (int i = t; i < NPTS; i += KT) {
        sx[i] = X[i]; sy[i] = X[NPTS + i]; sz[i] = X[2 * NPTS + i];
    }
    __syncthreads();

    float Px[RW], Py[RW], Pz[RW], Pw[RW];
#pragma unroll
    for (int r = 0; r < RW; ++r) {
        int rr = (row0 + r) & (NPTS - 1);
        Px[r] = sx[rr]; Py[r] = sy[rr]; Pz[r] = sz[rr];
        Pw[r] = (Px[r] * Px[r] + Py[r] * Py[r]) + Pz[r] * Pz[r];   // canonical
    }

    // ---- phase 1: per-lane chunk minima (FMA form; shared qw) ----
    float bm[RW];
#pragma unroll
    for (int r = 0; r < RW; ++r) bm[r] = __builtin_huge_valf();
    for (int i = 0; i < NPTS / 64; ++i) {
        int m = i * 64 + lane;
        float qx = sx[m], qy = sy[m], qz = sz[m];
        float qwF = __builtin_fmaf(qz, qz, __builtin_fmaf(qy, qy, qx * qx));
#pragma unroll
        for (int r = 0; r < RW; ++r) {
            float dot = __builtin_fmaf(qz, Pz[r],
                         __builtin_fmaf(qy, Py[r], qx * Px[r]));
            float d2  = __builtin_fmaf(-2.0f, dot, Pw[r] + qwF);
            bm[r] = fminf(bm[r], d2);
        }
    }
    // Slacked thresholds: cover canonical-vs-FMA rounding differences
    // (|d2| <= ~60 here; worst-case reassoc error << 1e-4).
    float T[RW];
#pragma unroll
    for (int r = 0; r < RW; ++r) {
        float tt = thresh16(bm[r], lane);
        T[r] = tt + (fabsf(tt) * 4e-6f + 1e-4f);
    }

    // ---- phase 2: filter candidates (FMA form; skip empty ballots) ----
    int cc[RW];
#pragma unroll
    for (int r = 0; r < RW; ++r) cc[r] = 0;
    for (int i = 0; i < NPTS / 64; ++i) {
        int m = i * 64 + lane;
        float qx = sx[m], qy = sy[m], qz = sz[m];
        float qwF = __builtin_fmaf(qz, qz, __builtin_fmaf(qy, qy, qx * qx));
#pragma unroll
        for (int r = 0; r < RW; ++r) {
            float dot = __builtin_fmaf(qz, Pz[r],
                         __builtin_fmaf(qy, Py[r], qx * Px[r]));
            float d2  = __builtin_fmaf(-2.0f, dot, Pw[r] + qwF);
            bool pass = d2 <= T[r];
            unsigned long long bal = __ballot(pass);
            if (bal) {                              // wave-uniform skip
                if (pass) {
                    int pos = cc[r] + __popcll(bal & ((1ull << lane) - 1ull));
                    if (pos < CAP) lists[wv * RW + r][pos] = m;
                }
                cc[r] += (int)__popcll(bal);
            }
        }
    }

    // ---- phase 3 + outputs (canonical keys/weights) ----
#pragma unroll
    for (int r = 0; r < RW; ++r) {
        float4 P = make_float4(Px[r], Py[r], Pz[r], Pw[r]);
        int sel = select16(sx, sy, sz, &lists[wv * RW + r][0], cc[r], P, lane);
        emit_row(row0 + r, b, sel, P, sx, sy, sz, Dsum, idx_out, w_out,
                 cnt, inc, spillc, spill, do_inc, lane);
    }
}

// ---------------------------------------------------------------------------
// row_kernel (R9/R10-verified, 51.4 us ~ write floor)
// ---------------------------------------------------------------------------
__global__ __launch_bounds__(1024, 4) void row_kernel(const int* __restrict__ idxb,
                                                      const float* __restrict__ wb,
                                                      const float* __restrict__ Dsum,
                                                      const int* __restrict__ cnt,
                                                      const int* __restrict__ inc,
                                                      const int* __restrict__ spillc,
                                                      const int* __restrict__ spill,
                                                      float* __restrict__ L) {
    __shared__ float row[RROWS * NPTS];          // 64 KB
    const int r0 = blockIdx.x * RROWS;           // first global row
    const int b  = r0 >> 12;

    float4* row4 = (float4*)row;
    for (int i = threadIdx.x; i < RROWS * NPTS / 4; i += 1024)
        row4[i] = make_float4(0.0f, 0.0f, 0.0f, 0.0f);
    __syncthreads();

    const int rr = threadIdx.x >> 8;             // 0..RROWS-1
    const int tt = threadIdx.x & 255;
    const int r  = r0 + rr;
    float* myrow = row + rr * NPTS;
    const float dn = disv(Dsum, r);

    if (tt < KNN) {                              // outgoing (unique cols)
        int g = r * KNN + tt;
        int j = idxb[g];
        float v = -0.5f * wb[g] * dn * disv(Dsum, (b << 12) + j);
        atomicAdd(&myrow[j], v);
    }
    int c = cnt[r];
    if (c > CAPIN) c = CAPIN;                    // overflow -> spill drain below
    for (int i = tt; i < c; i += 256) {          // incoming bucket
        int g   = inc[(size_t)r * CAPIN + i];
        int src = g >> 4;
        float v = -0.5f * wb[g] * disv(Dsum, src) * dn;
        atomicAdd(&myrow[src & (NPTS - 1)], v);
    }

    int sc = spillc[0];
    if (sc > 0) {
        if (sc > SPILLCAP) sc = SPILLCAP;
        for (int i = threadIdx.x; i < sc; i += 1024) {
            int g   = spill[i];
            int src = g >> 4;
            int jg  = ((src >> 12) << 12) + idxb[g];     // target row global
            if (jg >= r0 && jg < r0 + RROWS) {
                float v = -0.5f * wb[g] * disv(Dsum, src) * disv(Dsum, jg);
                atomicAdd(&row[(jg - r0) * NPTS + (src & (NPTS - 1))], v);
            }
        }
    }
    __syncthreads();

    const int n0 = r0 & (NPTS - 1);
    nfloat4* Lr = (nfloat4*)(L + (size_t)b * NPTS * NPTS + (size_t)n0 * NPTS);
    const nfloat4* row4n = (const nfloat4*)row;
    for (int q = threadIdx.x; q < RROWS * NPTS / 4; q += 1024) {
        nfloat4 v = row4n[q];
        int n = n0 + (q >> 10);                  // 1024 float4 per row
        if ((q & 1023) == (n >> 2)) v[n & 3] += 1.0f;
        __builtin_nontemporal_store(v, &Lr[q]);
    }
}

// ---------------------------------------------------------------------------
// Fallback path (small workspace): dense fill + global-atomic scatter.
// ---------------------------------------------------------------------------
__global__ void dis_kernel(const float* __restrict__ Dsum, float* __restrict__ dis, int n) {
    int i = blockIdx.x * blockDim.x + threadIdx.x;
    if (i < n) dis[i] = 1.0f / sqrtf(fmaxf(Dsum[i], 1e-6f));
}

__global__ __launch_bounds__(256) void fill_kernel(float4* __restrict__ L4, size_t T4) {
    size_t g4     = (size_t)blockIdx.x * blockDim.x + threadIdx.x;
    size_t stride = (size_t)gridDim.x * blockDim.x;
    for (; g4 < T4; g4 += stride) {
        size_t g = g4 << 2;
        int o    = (int)(g & (size_t)(NPTS * (size_t)NPTS - 1));
        int row  = o >> 12;
        int col0 = o & (NPTS - 1);
        float4 v;
        v.x = (row == col0    ) ? 1.0f : 0.0f;
        v.y = (row == col0 + 1) ? 1.0f : 0.0f;
        v.z = (row == col0 + 2) ? 1.0f : 0.0f;
        v.w = (row == col0 + 3) ? 1.0f : 0.0f;
        L4[g4] = v;
    }
}

__global__ __launch_bounds__(256) void scatter_kernel(const int* __restrict__ idxb,
                                                      const float* __restrict__ wb,
                                                      const float* __restrict__ dis,
                                                      float* __restrict__ L) {
    int g   = blockIdx.x * 256 + threadIdx.x;
    int row = g >> 4;
    int b   = row >> 12;
    int n   = row & (NPTS - 1);
    int j   = idxb[g];
    float v = -0.5f * wb[g] * dis[row] * dis[(b << 12) + j];
    float* Lb = L + (size_t)b * NPTS * NPTS;
    atomicAdd(Lb + (size_t)n * NPTS + j, v);
    atomicAdd(Lb + (size_t)j * NPTS + n, v);
}

// ---------------------------------------------------------------------------
extern "C" void kernel_launch(void* const* d_in, const int* in_sizes, int n_in,
                              void* d_out, int out_size, void* d_ws, size_t ws_size,
                              hipStream_t stream) {
    const float* xyz = (const float*)d_in[0];
    const int B  = in_sizes[0] / (3 * NPTS);            // 4
    const int BN = B * NPTS;                            // 16384

    float* Dsum   = (float*)d_ws;
    int*   cnt    = (int*)(Dsum + BN);
    int*   spillc = cnt + BN;
    int*   idxb   = (int*)(spillc + 16);
    float* wb     = (float*)(idxb + (size_t)BN * KNN);
    int*   inc    = (int*)(wb + (size_t)BN * KNN);
    int*   spill  = inc + (size_t)BN * CAPIN;
    float* L      = (float*)d_out;

    size_t need = ((size_t)BN * (2 + 2 * KNN + CAPIN) + 16 + SPILLCAP) * 4;
    const int fused = (ws_size >= need);

    if (fused) {
        int nz = 2 * BN + 16;                           // Dsum + cnt + spillc
        zero_kernel<<<(nz + 255) / 256, 256, 0, stream>>>(Dsum, nz);
        knn_kernel<<<BN / RPBK, KT, 0, stream>>>(xyz, Dsum, idxb, wb,
                                                 cnt, inc, spillc, spill, 1);
        row_kernel<<<BN / RROWS, 1024, 0, stream>>>(idxb, wb, Dsum,
                                                    cnt, inc, spillc, spill, L);
    } else {
        // fallback: fill + scatter (~2.25 MB workspace)
        float* fDsum = (float*)d_ws;
        float* fdis  = fDsum + BN;
        int*   fidx  = (int*)(fdis + BN);
        float* fwb   = (float*)(fidx + (size_t)BN * KNN);
        zero_kernel<<<BN / 256, 256, 0, stream>>>(fDsum, BN);
        knn_kernel<<<BN / RPBK, KT, 0, stream>>>(xyz, fDsum, fidx, fwb,
                                                 nullptr, nullptr, nullptr, nullptr, 0);
        dis_kernel<<<BN / 256, 256, 0, stream>>>(fDsum, fdis, BN);
        size_t T4 = (size_t)B * NPTS * NPTS / 4;
        fill_kernel<<<8192, 256, 0, stream>>>((float4*)d_out, T4);
        scatter_kernel<<<(BN * KNN) / 256, 256, 0, stream>>>(fidx, fwb, fdis, L);
    }
}